// Round 1
// 471.661 us; speedup vs baseline: 1.0484x; 1.0484x over previous
//
#include <hip/hip_runtime.h>

#define S_LEN 2048
#define DMODEL 1024
#define NHEADS 8
#define DK 128
#define BATCH 2

typedef _Float16 h16;
typedef __attribute__((ext_vector_type(8))) _Float16 half8v;
typedef __attribute__((ext_vector_type(4))) float float4v;

// async global->LDS, 16B per lane; LDS dest = uniform base + lane*16
#define GLD16(gp, lp)                                                  \
  __builtin_amdgcn_global_load_lds(                                    \
      (const __attribute__((address_space(1))) void*)(gp),             \
      (__attribute__((address_space(3))) void*)(lp), 16, 0, 0)

// ---------------------------------------------------------------------------
// Fused fp32 -> fp16 pre-conversion for all 7 tensors, one launch.
// 8-elem units: 3 token tensors (524288 units each) + 4 weights (131072 each)
// = 2097152 units = 8192 blocks x 256, exact (no guard).
// ---------------------------------------------------------------------------
__global__ __launch_bounds__(256) void cvt_all(
    const float* __restrict__ q, const float* __restrict__ k, const float* __restrict__ v,
    const float* __restrict__ wq, const float* __restrict__ wk, const float* __restrict__ wv,
    const float* __restrict__ wo,
    h16* __restrict__ dq, h16* __restrict__ dk, h16* __restrict__ dv,
    h16* __restrict__ dwq, h16* __restrict__ dwk, h16* __restrict__ dwv,
    h16* __restrict__ dwo) {
  int i = blockIdx.x * 256 + threadIdx.x;
  const float* src;
  h16* dst;
  int off;
  if (i < 1572864) {
    int seg = i >> 19;
    off = i & 524287;
    src = seg == 0 ? q : (seg == 1 ? k : v);
    dst = seg == 0 ? dq : (seg == 1 ? dk : dv);
  } else {
    int j = i - 1572864;
    int seg = j >> 17;
    off = j & 131071;
    src = seg == 0 ? wq : (seg == 1 ? wk : (seg == 2 ? wv : wo));
    dst = seg == 0 ? dwq : (seg == 1 ? dwk : (seg == 2 ? dwv : dwo));
  }
  const float4* s = (const float4*)src + (size_t)off * 2;
  float4 a = s[0], b = s[1];
  half8v h = {(h16)a.x, (h16)a.y, (h16)a.z, (h16)a.w,
              (h16)b.x, (h16)b.y, (h16)b.z, (h16)b.w};
  *((half8v*)dst + off) = h;
}

// ---------------------------------------------------------------------------
// Fused Q/K/V projection GEMM. C[4096,1024] = A @ W^T + b, tile 128x128 BK=32,
// 4 waves 2x2. blockIdx.z selects {Q,K,V}. grid (8,32,3) = 768 blocks (3/CU).
// LDS tiles [128][32] fp16 staged via global_load_lds, chunk-slot XOR swizzle.
// z=0,1: scatter fp16 [B,H,S,dk]; z=2: scatter fp16 [B,H,dk,S] (V transposed).
// ---------------------------------------------------------------------------
__global__ __launch_bounds__(256) void qkv_gemm(
    const h16* __restrict__ qf, const h16* __restrict__ kf, const h16* __restrict__ vf,
    const h16* __restrict__ wq, const h16* __restrict__ wk, const h16* __restrict__ wv,
    const float* __restrict__ bq, const float* __restrict__ bk, const float* __restrict__ bv,
    h16* __restrict__ qh, h16* __restrict__ kh, h16* __restrict__ vt) {
  __shared__ h16 As[128 * 32];
  __shared__ h16 Bs[128 * 32];

  const int z = blockIdx.z;
  const h16* A = z == 0 ? qf : (z == 1 ? kf : vf);
  const h16* Bw = z == 0 ? wq : (z == 1 ? wk : wv);
  const float* bias = z == 0 ? bq : (z == 1 ? bk : bv);
  h16* outp = z == 0 ? qh : (z == 1 ? kh : vt);

  const int t = threadIdx.x, lane = t & 63, w = t >> 6;
  const int m0 = blockIdx.y * 128, n0 = blockIdx.x * 128;
  const int wm = (w >> 1) * 64, wn = (w & 1) * 64;
  const int lcol = lane & 15, lquad = lane >> 4;

  float4v acc[4][4];
  for (int i = 0; i < 4; ++i)
    for (int j = 0; j < 4; ++j) acc[i][j] = {0.f, 0.f, 0.f, 0.f};

  for (int kt = 0; kt < 1024; kt += 32) {
    __syncthreads();
    for (int j = 0; j < 2; ++j) {
      int i = w * 2 + j;
      int row = i * 16 + (lane >> 2);
      int c4 = (lane & 3) ^ ((row >> 1) & 3);
      GLD16(A + (size_t)(m0 + row) * 1024 + kt + c4 * 8, As + i * 512);
      GLD16(Bw + (size_t)(n0 + row) * 1024 + kt + c4 * 8, Bs + i * 512);
    }
    __syncthreads();

    half8v af[4], bf[4];
    for (int mi = 0; mi < 4; ++mi) {
      int r = wm + mi * 16 + lcol;
      af[mi] = *(const half8v*)(As + r * 32 + ((lquad ^ ((r >> 1) & 3)) << 3));
    }
    for (int ni = 0; ni < 4; ++ni) {
      int r = wn + ni * 16 + lcol;
      bf[ni] = *(const half8v*)(Bs + r * 32 + ((lquad ^ ((r >> 1) & 3)) << 3));
    }
    for (int mi = 0; mi < 4; ++mi)
      for (int ni = 0; ni < 4; ++ni)
        acc[mi][ni] = __builtin_amdgcn_mfma_f32_16x16x32_f16(af[mi], bf[ni],
                                                             acc[mi][ni], 0, 0, 0);
  }

  for (int ni = 0; ni < 4; ++ni) {
    int gn = n0 + wn + ni * 16 + lcol;
    float bvv = bias[gn];
    int hh = gn >> 7, dv = gn & 127;
    for (int mi = 0; mi < 4; ++mi) {
      int gmb = m0 + wm + mi * 16 + lquad * 4;
      for (int r = 0; r < 4; ++r) {
        int gm = gmb + r;
        float v = acc[mi][ni][r] + bvv;
        int b = gm >> 11, s = gm & 2047;
        if (z < 2)
          outp[((size_t)(b * NHEADS + hh) * S_LEN + s) * DK + dv] = (h16)v;
        else
          outp[((size_t)(b * NHEADS + hh) * DK + dv) * S_LEN + s] = (h16)v;
      }
    }
  }
}

// ---------------------------------------------------------------------------
// Output projection GEMM: out[4096,1024] = ctx @ Wo^T + bo, fp32 out.
// ---------------------------------------------------------------------------
__global__ __launch_bounds__(256) void out_gemm(const h16* __restrict__ A,
                                                const h16* __restrict__ Bw,
                                                const float* __restrict__ bias,
                                                float* __restrict__ C) {
  __shared__ h16 As[64 * 32];
  __shared__ h16 Bs[128 * 32];

  const int t = threadIdx.x, lane = t & 63, w = t >> 6;
  const int m0 = blockIdx.y * 64, n0 = blockIdx.x * 128;
  const int wm = (w >> 1) * 32, wn = (w & 1) * 64;
  const int lcol = lane & 15, lquad = lane >> 4;

  float4v acc[2][4];
  for (int i = 0; i < 2; ++i)
    for (int j = 0; j < 4; ++j) acc[i][j] = {0.f, 0.f, 0.f, 0.f};

  for (int kt = 0; kt < 1024; kt += 32) {
    __syncthreads();
    {
      int i = w;
      int row = i * 16 + (lane >> 2);
      int c4 = (lane & 3) ^ ((row >> 1) & 3);
      GLD16(A + (size_t)(m0 + row) * 1024 + kt + c4 * 8, As + i * 512);
    }
    for (int j = 0; j < 2; ++j) {
      int i = w * 2 + j;
      int row = i * 16 + (lane >> 2);
      int c4 = (lane & 3) ^ ((row >> 1) & 3);
      GLD16(Bw + (size_t)(n0 + row) * 1024 + kt + c4 * 8, Bs + i * 512);
    }
    __syncthreads();

    half8v af[2], bf[4];
    for (int mi = 0; mi < 2; ++mi) {
      int r = wm + mi * 16 + lcol;
      af[mi] = *(const half8v*)(As + r * 32 + ((lquad ^ ((r >> 1) & 3)) << 3));
    }
    for (int ni = 0; ni < 4; ++ni) {
      int r = wn + ni * 16 + lcol;
      bf[ni] = *(const half8v*)(Bs + r * 32 + ((lquad ^ ((r >> 1) & 3)) << 3));
    }
    for (int mi = 0; mi < 2; ++mi)
      for (int ni = 0; ni < 4; ++ni)
        acc[mi][ni] = __builtin_amdgcn_mfma_f32_16x16x32_f16(af[mi], bf[ni],
                                                             acc[mi][ni], 0, 0, 0);
  }

  for (int ni = 0; ni < 4; ++ni) {
    int gn = n0 + wn + ni * 16 + lcol;
    float bvv = bias[gn];
    for (int mi = 0; mi < 2; ++mi) {
      int gmb = m0 + wm + mi * 16 + lquad * 4;
      for (int r = 0; r < 4; ++r)
        C[(size_t)(gmb + r) * 1024 + gn] = acc[mi][ni][r] + bvv;
    }
  }
}

// XCD-aware block swizzle: grid (32,16)=512. xcd = id&7 handles bh in
// {xcd, xcd+8} only -> 2 MB K/V per XCD, L2-resident.
__device__ inline void attn_bid(int& bh, int& q0) {
  int id = blockIdx.y * 32 + blockIdx.x;
  int xcd = id & 7, rank = id >> 3;
  bh = xcd + 8 * (rank >> 5);
  q0 = (rank & 31) * 64;
}

// PV update: cacc += P(frag from PP) @ V(frag from VV). Wave w owns d-cols
// [32w,32w+32). ap frag reuse=2 (k2), bv frag reuse=4 (mi).
#define PV_STEP(PP, VV)                                                        \
  {                                                                            \
    half8v ap[4][2];                                                           \
    for (int mi = 0; mi < 4; ++mi)                                             \
      for (int k2 = 0; k2 < 2; ++k2)                                           \
        ap[mi][k2] =                                                           \
            *(const half8v*)((PP) + (mi * 16 + lcol) * 72 + k2 * 32 + lquad * 8); \
    for (int nd = 0; nd < 2; ++nd) {                                           \
      int r = w * 32 + nd * 16 + lcol;                                         \
      for (int k2 = 0; k2 < 2; ++k2) {                                         \
        half8v bv = *(const half8v*)((VV) + r * 64 +                           \
                                     (((k2 * 4 + lquad) ^ (r & 7)) << 3));     \
        for (int mi = 0; mi < 4; ++mi)                                         \
          cacc[mi][nd] = __builtin_amdgcn_mfma_f32_16x16x32_f16(               \
              ap[mi][k2], bv, cacc[mi][nd], 0, 0, 0);                          \
      }                                                                        \
    }                                                                          \
  }

// ---------------------------------------------------------------------------
// Fused attention: one block = (bh, 64 q-rows), 4 waves, Q fully in registers.
// Phase 1: l[row] = sum_k exp(q.k*scale). Wave w owns score-cols [16w,16w+16)
//   (bk reads /4 vs row-split), reduce over lcol lanes + cross-wave LDS.
// Phase 2: pipelined QK(kt) || PV(kt-1), double-buffered Vts/Ps, 2 barriers/kt.
//   P written exact fp32 to attn and fp16 to Ps for the PV MFMA.
// ---------------------------------------------------------------------------
__global__ __launch_bounds__(256, 2) void attn_fused(
    const h16* __restrict__ qh, const h16* __restrict__ kh,
    const h16* __restrict__ vt, float* __restrict__ attn,
    h16* __restrict__ ctxb) {
  __shared__ h16 Ks[64 * 128];        // K tile; also Q preload staging
  __shared__ h16 Vts[2][128 * 64];    // V^T tiles, double-buffered
  __shared__ h16 Ps[2][64 * 72];      // P tiles (pitch 72), double-buffered

  const int t = threadIdx.x, lane = t & 63, w = t >> 6;
  const int lcol = lane & 15, lquad = lane >> 4;
  int bh, q0;
  attn_bid(bh, q0);
  const int b = bh >> 3, h = bh & 7;
  const float scale = 0.08838834764831845f;

  // ---- Q preload into registers (staged through Ks) ----
  for (int j = 0; j < 4; ++j) {
    int i = w * 4 + j;
    int row = i * 4 + (lane >> 4);
    int c4 = (lane & 15) ^ (row & 7);
    GLD16(qh + ((size_t)bh * S_LEN + q0 + row) * DK + c4 * 8, Ks + i * 512);
  }
  __syncthreads();
  half8v aq[4][4];
  for (int mi = 0; mi < 4; ++mi) {
    int r = mi * 16 + lcol;
    for (int ks = 0; ks < 4; ++ks)
      aq[mi][ks] = *(const half8v*)(Ks + r * 128 + (((ks * 4 + lquad) ^ (r & 7)) << 3));
  }

  // ---- Phase 1: row sums ----
  float ls[4][4];
  for (int mi = 0; mi < 4; ++mi)
    for (int rr = 0; rr < 4; ++rr) ls[mi][rr] = 0.f;

  for (int kt = 0; kt < 32; ++kt) {
    __syncthreads();
    for (int j = 0; j < 4; ++j) {
      int i = w * 4 + j;
      int row = i * 4 + (lane >> 4);
      int c4 = (lane & 15) ^ (row & 7);
      GLD16(kh + ((size_t)bh * S_LEN + kt * 64 + row) * DK + c4 * 8, Ks + i * 512);
    }
    __syncthreads();

    float4v sacc[4];
    for (int mi = 0; mi < 4; ++mi) sacc[mi] = {0.f, 0.f, 0.f, 0.f};
    int r = w * 16 + lcol;
    for (int ks = 0; ks < 4; ++ks) {
      half8v bk = *(const half8v*)(Ks + r * 128 + (((ks * 4 + lquad) ^ (r & 7)) << 3));
      for (int mi = 0; mi < 4; ++mi)
        sacc[mi] = __builtin_amdgcn_mfma_f32_16x16x32_f16(aq[mi][ks], bk, sacc[mi], 0, 0, 0);
    }
    for (int mi = 0; mi < 4; ++mi)
      for (int rr = 0; rr < 4; ++rr) ls[mi][rr] += __expf(sacc[mi][rr] * scale);
  }

  // reduce: over lcol lanes (wave's 16 cols), then cross-wave via LDS
  float* red = (float*)Ps[0];  // [4 waves][64 rows]
  for (int mi = 0; mi < 4; ++mi)
    for (int rr = 0; rr < 4; ++rr) {
      float vsum = ls[mi][rr];
      for (int off = 1; off < 16; off <<= 1) vsum += __shfl_xor(vsum, off);
      if (lcol == 0) red[w * 64 + mi * 16 + lquad * 4 + rr] = vsum;
    }
  __syncthreads();
  float il[4][4];
  for (int mi = 0; mi < 4; ++mi)
    for (int rr = 0; rr < 4; ++rr) {
      int row = mi * 16 + lquad * 4 + rr;
      il[mi][rr] = 1.f / (red[row] + red[64 + row] + red[128 + row] + red[192 + row]);
    }

  // ---- Phase 2: pipelined QK/P || PV ----
  float4v cacc[4][2];
  for (int mi = 0; mi < 4; ++mi)
    for (int nd = 0; nd < 2; ++nd) cacc[mi][nd] = {0.f, 0.f, 0.f, 0.f};

  float* abase = attn + ((size_t)bh * S_LEN + q0 + lquad * 4) * S_LEN + w * 16 + lcol;

  for (int kt = 0; kt < 32; ++kt) {
    int p = kt & 1;
    __syncthreads();
    for (int j = 0; j < 4; ++j) {
      int i = w * 4 + j;
      int row = i * 4 + (lane >> 4);
      int c4 = (lane & 15) ^ (row & 7);
      GLD16(kh + ((size_t)bh * S_LEN + kt * 64 + row) * DK + c4 * 8, Ks + i * 512);
    }
    for (int j = 0; j < 4; ++j) {
      int i = w * 4 + j;
      int row = i * 8 + (lane >> 3);
      int c4 = (lane & 7) ^ (row & 7);
      GLD16(vt + ((size_t)bh * DK + row) * S_LEN + kt * 64 + c4 * 8, Vts[p] + i * 512);
    }
    __syncthreads();

    // PV for previous tile (independent of this tile's QK -> ILP)
    if (kt > 0) {
      const h16* Psr = Ps[p ^ 1];
      const h16* Vr = Vts[p ^ 1];
      PV_STEP(Psr, Vr);
    }

    // QK for current tile
    float4v sacc[4];
    for (int mi = 0; mi < 4; ++mi) sacc[mi] = {0.f, 0.f, 0.f, 0.f};
    {
      int r = w * 16 + lcol;
      for (int ks = 0; ks < 4; ++ks) {
        half8v bk = *(const half8v*)(Ks + r * 128 + (((ks * 4 + lquad) ^ (r & 7)) << 3));
        for (int mi = 0; mi < 4; ++mi)
          sacc[mi] = __builtin_amdgcn_mfma_f32_16x16x32_f16(aq[mi][ks], bk, sacc[mi], 0, 0, 0);
      }
    }

    // P-phase: exact fp32 attn + fp16 Ps[p]
    h16* Psw = Ps[p] + lquad * 4 * 72 + w * 16 + lcol;
    float* ab = abase + (size_t)kt * 64;
    for (int mi = 0; mi < 4; ++mi)
      for (int rr = 0; rr < 4; ++rr) {
        float pv = __expf(sacc[mi][rr] * scale) * il[mi][rr];
        ab[(size_t)(mi * 16 + rr) * S_LEN] = pv;
        Psw[(mi * 16 + rr) * 72] = (h16)pv;
      }
  }

  // epilogue: PV for last tile (kt=31 wrote parity 1)
  __syncthreads();
  {
    const h16* Psr = Ps[1];
    const h16* Vr = Vts[1];
    PV_STEP(Psr, Vr);
  }

  h16* cb = ctxb + ((size_t)b * S_LEN + q0 + lquad * 4) * DMODEL + h * DK + w * 32;
  for (int mi = 0; mi < 4; ++mi)
    for (int nd = 0; nd < 2; ++nd)
      for (int rr = 0; rr < 4; ++rr)
        cb[(size_t)(mi * 16 + rr) * DMODEL + nd * 16 + lcol] = (h16)cacc[mi][nd][rr];
}

// ---------------------------------------------------------------------------
extern "C" void kernel_launch(void* const* d_in, const int* in_sizes, int n_in,
                              void* d_out, int out_size, void* d_ws, size_t ws_size,
                              hipStream_t stream) {
  const float* Q  = (const float*)d_in[0];
  const float* K  = (const float*)d_in[1];
  const float* V  = (const float*)d_in[2];
  const float* Wq = (const float*)d_in[3];
  const float* bq = (const float*)d_in[4];
  const float* Wk = (const float*)d_in[5];
  const float* bk = (const float*)d_in[6];
  const float* Wv = (const float*)d_in[7];
  const float* bv = (const float*)d_in[8];
  const float* Wo = (const float*)d_in[9];
  const float* bo = (const float*)d_in[10];

  float* out  = (float*)d_out;
  float* attn = out + (size_t)BATCH * S_LEN * DMODEL;

  const size_t NTOK = (size_t)BATCH * S_LEN * DMODEL;  // 4194304
  const size_t NW = (size_t)DMODEL * DMODEL;           // 1048576
  h16* qf  = (h16*)d_ws;        // later aliased as ctxb
  h16* kf  = qf + NTOK;
  h16* vf  = kf + NTOK;
  h16* wqh = vf + NTOK;
  h16* wkh = wqh + NW;
  h16* wvh = wkh + NW;
  h16* woh = wvh + NW;
  h16* qh  = woh + NW;
  h16* kh  = qh + NTOK;
  h16* vt  = kh + NTOK;
  h16* ctxb = qf;               // safe: qf consumed before attn_fused runs

  dim3 gb(256);
  cvt_all<<<dim3(8192), gb, 0, stream>>>(Q, K, V, Wq, Wk, Wv, Wo,
                                         qf, kf, vf, wqh, wkh, wvh, woh);
  qkv_gemm<<<dim3(8, 32, 3), gb, 0, stream>>>(qf, kf, vf, wqh, wkh, wvh,
                                              bq, bk, bv, qh, kh, vt);
  attn_fused<<<dim3(32, 16), gb, 0, stream>>>(qh, kh, vt, attn, ctxb);
  out_gemm<<<dim3(8, 64), gb, 0, stream>>>(ctxb, woh, bo, out);
}